// Round 1
// baseline (7393.761 us; speedup 1.0000x reference)
//
#include <hip/hip_runtime.h>

// Problem constants
#define B_   16
#define C_   96
#define H_   128
#define W_   128
#define HW_  16384          // 128*128
#define GROUPS_ 4
#define CPG_ 24             // channels per group
#define NPG_ 393216.0f      // CPG_*HW_ elements per (batch, group)
#define TDIM_ 256
#define HEADS_ 16
#define HD_ 6
#define WS_ 8
#define L_  64              // WS*WS

__device__ __forceinline__ float silu_f(float x) {
    return x / (1.f + __expf(-x));
}

// ---------------------------------------------------------------------------
// t = silu(t_emb @ wt.T + bt)   -> tvec[B][192]
// ---------------------------------------------------------------------------
__global__ void temb_kernel(const float* __restrict__ t_emb,
                            const float* __restrict__ wt,
                            const float* __restrict__ bt,
                            float* __restrict__ tvec) {
    int idx = blockIdx.x * 256 + threadIdx.x;   // 16*192 = 3072
    if (idx >= B_ * 192) return;
    int b = idx / 192, o = idx - b * 192;
    float a = bt[o];
    const float* te = t_emb + b * TDIM_;
    const float* wr = wt + o * TDIM_;
    for (int k = 0; k < TDIM_; ++k) a += te[k] * wr[k];
    tvec[idx] = silu_f(a);
}

// ---------------------------------------------------------------------------
// conv3x3 (pad 1) + bias, also accumulates per-(b,group) sum/sumsq into stats.
// One block: 16x16 output tile, all 96 out channels per thread (acc[96] regs).
// Input channels staged in LDS in chunks of 32 (18x18 halo tile).
// ---------------------------------------------------------------------------
__global__ __launch_bounds__(256, 2)
void conv3x3_kernel(const float* __restrict__ in, const float* __restrict__ w,
                    const float* __restrict__ bias, float* __restrict__ out,
                    float* __restrict__ stats /* [B][4][2] */) {
    __shared__ float tile[32 * 18 * 18];
    const int b   = blockIdx.z;
    const int ty0 = blockIdx.y * 16;
    const int tx0 = blockIdx.x * 16;
    const int tid = threadIdx.x;
    const int tx  = tid & 15, ty = tid >> 4;

    float acc[96];
#pragma unroll
    for (int i = 0; i < 96; ++i) acc[i] = 0.f;

    for (int icb = 0; icb < C_; icb += 32) {
        __syncthreads();
        for (int idx = tid; idx < 32 * 324; idx += 256) {
            int ic  = idx / 324;
            int rem = idx - ic * 324;
            int yy  = rem / 18;
            int xx  = rem - yy * 18;
            int gy = ty0 + yy - 1, gx = tx0 + xx - 1;
            float v = 0.f;
            if (gy >= 0 && gy < H_ && gx >= 0 && gx < W_)
                v = in[((b * C_ + icb + ic) * H_ + gy) * W_ + gx];
            tile[idx] = v;
        }
        __syncthreads();
#pragma unroll 1
        for (int ic = 0; ic < 32; ++ic) {
            const float* tp = &tile[ic * 324 + ty * 18 + tx];
            float t9[9];
            t9[0] = tp[0];      t9[1] = tp[1];      t9[2] = tp[2];
            t9[3] = tp[18];     t9[4] = tp[19];     t9[5] = tp[20];
            t9[6] = tp[36];     t9[7] = tp[37];     t9[8] = tp[38];
            const int icg = icb + ic;
#pragma unroll
            for (int oc = 0; oc < 96; ++oc) {
                const float* wo = w + (oc * C_ + icg) * 9;
                float a = acc[oc];
                a += wo[0]*t9[0]; a += wo[1]*t9[1]; a += wo[2]*t9[2];
                a += wo[3]*t9[3]; a += wo[4]*t9[4]; a += wo[5]*t9[5];
                a += wo[6]*t9[6]; a += wo[7]*t9[7]; a += wo[8]*t9[8];
                acc[oc] = a;
            }
        }
    }

    const int gy = ty0 + ty, gx = tx0 + tx;
    const int base = ((b * C_) * H_ + gy) * W_ + gx;
    float sg[4]  = {0.f, 0.f, 0.f, 0.f};
    float ssg[4] = {0.f, 0.f, 0.f, 0.f};
#pragma unroll
    for (int oc = 0; oc < 96; ++oc) {
        float v = acc[oc] + bias[oc];
        out[base + oc * HW_] = v;
        sg[oc / CPG_]  += v;
        ssg[oc / CPG_] += v * v;
    }
#pragma unroll
    for (int g = 0; g < 4; ++g) {
        float s = sg[g], ss = ssg[g];
        for (int off = 32; off > 0; off >>= 1) {
            s  += __shfl_down(s, off, 64);
            ss += __shfl_down(ss, off, 64);
        }
        if ((tid & 63) == 0) {
            atomicAdd(&stats[(b * 4 + g) * 2 + 0], s);
            atomicAdd(&stats[(b * 4 + g) * 2 + 1], ss);
        }
    }
}

// ---------------------------------------------------------------------------
// h = silu(GN(y; stats1, g1, be1)) * (1 + shift[b,c]) + bias[b,c]
// emits h and accumulates stats2 (sum/sumsq of h per (b,group)).
// One block per (b,c) plane.
// ---------------------------------------------------------------------------
__global__ void apply1_kernel(const float* __restrict__ y,
                              const float* __restrict__ stats1,
                              const float* __restrict__ g1,
                              const float* __restrict__ be1,
                              const float* __restrict__ tvec,
                              float* __restrict__ h,
                              float* __restrict__ stats2) {
    const int bc = blockIdx.x;
    const int b = bc / C_, c = bc - b * C_;
    const int g = c / CPG_;
    const float sum = stats1[(b * 4 + g) * 2], sumsq = stats1[(b * 4 + g) * 2 + 1];
    const float mean = sum / NPG_;
    const float var  = sumsq / NPG_ - mean * mean;
    const float rstd = rsqrtf(var + 1e-5f);
    const float sc = rstd * g1[c];
    const float sh = be1[c] - mean * sc;
    const float tsc = 1.f + tvec[b * 192 + c];
    const float tbi = tvec[b * 192 + 96 + c];

    const float4* yp = (const float4*)(y + (size_t)bc * HW_);
    float4* hp = (float4*)(h + (size_t)bc * HW_);
    float ls = 0.f, lss = 0.f;
    for (int i = threadIdx.x; i < HW_ / 4; i += 256) {
        float4 v = yp[i];
        float r0 = silu_f(v.x * sc + sh) * tsc + tbi;
        float r1 = silu_f(v.y * sc + sh) * tsc + tbi;
        float r2 = silu_f(v.z * sc + sh) * tsc + tbi;
        float r3 = silu_f(v.w * sc + sh) * tsc + tbi;
        hp[i] = make_float4(r0, r1, r2, r3);
        ls  += r0 + r1 + r2 + r3;
        lss += r0*r0 + r1*r1 + r2*r2 + r3*r3;
    }
    for (int off = 32; off > 0; off >>= 1) {
        ls  += __shfl_down(ls, off, 64);
        lss += __shfl_down(lss, off, 64);
    }
    if ((threadIdx.x & 63) == 0) {
        atomicAdd(&stats2[(b * 4 + g) * 2 + 0], ls);
        atomicAdd(&stats2[(b * 4 + g) * 2 + 1], lss);
    }
}

// ---------------------------------------------------------------------------
// out = GN(in; stats, gamma, beta), optional silu.  One block per (b,c).
// ---------------------------------------------------------------------------
__global__ void gn_apply_kernel(const float* __restrict__ in,
                                const float* __restrict__ stats,
                                const float* __restrict__ gamma,
                                const float* __restrict__ beta,
                                float* __restrict__ out, int dosilu) {
    const int bc = blockIdx.x;
    const int b = bc / C_, c = bc - b * C_;
    const int g = c / CPG_;
    const float sum = stats[(b * 4 + g) * 2], sumsq = stats[(b * 4 + g) * 2 + 1];
    const float mean = sum / NPG_;
    const float var  = sumsq / NPG_ - mean * mean;
    const float rstd = rsqrtf(var + 1e-5f);
    const float sc = rstd * gamma[c];
    const float sh = beta[c] - mean * sc;
    const float4* ip = (const float4*)(in + (size_t)bc * HW_);
    float4* op = (float4*)(out + (size_t)bc * HW_);
    for (int i = threadIdx.x; i < HW_ / 4; i += 256) {
        float4 v = ip[i];
        float r0 = v.x * sc + sh, r1 = v.y * sc + sh;
        float r2 = v.z * sc + sh, r3 = v.w * sc + sh;
        if (dosilu) { r0 = silu_f(r0); r1 = silu_f(r1); r2 = silu_f(r2); r3 = silu_f(r3); }
        op[i] = make_float4(r0, r1, r2, r3);
    }
}

// ---------------------------------------------------------------------------
// Fused window attention (channel-attention inside 8x8 windows):
//   qkv = Wqkv @ x_win ; per head: S = (Q K^T)*scale (6x6), softmax over e,
//   O = S V ; proj accumulated in registers ; outacc += 0.5*(proj + proj_b).
// Shift s handles the rolled branch: pixel = (win*8 + r + s) mod 128 for both
// read and write (roll(-s) -> window -> roll(+s) composes to this).
// Block: 192 threads = 3 waves (wave w computes q/k/v rows for w=0/1/2 and
// holds proj accumulator rows [w*32, w*32+32)).
// ---------------------------------------------------------------------------
__global__ __launch_bounds__(192, 2)
void winattn_kernel(const float* __restrict__ xin,
                    const float* __restrict__ qw, const float* __restrict__ qb,
                    const float* __restrict__ pw, const float* __restrict__ pb,
                    float* __restrict__ outacc, int shift) {
    __shared__ float xw[96][64];
    __shared__ float qkvh[3][6][64];
    __shared__ float sraw[6][6];
    __shared__ float attw[6][6];

    const int b = blockIdx.z, wi = blockIdx.y, wj = blockIdx.x;
    const int tid = threadIdx.x;
    const int w = tid >> 6, l = tid & 63;
    const int r = l >> 3, cc = l & 7;
    const int gy = (wi * 8 + r + shift) & 127;
    const int gx = (wj * 8 + cc + shift) & 127;

    for (int ch = w; ch < 96; ch += 3)
        xw[ch][l] = xin[((b * C_ + ch) * H_ + gy) * W_ + gx];

    float accp[32];
#pragma unroll
    for (int j = 0; j < 32; ++j) accp[j] = 0.f;
    __syncthreads();

    const float scale = 0.40824829046386302f;  // 6^{-1/2}

    for (int h = 0; h < HEADS_; ++h) {
        const int obase = w * 96 + h * 6;      // q rows / k rows / v rows per wave
        float a6[6];
#pragma unroll
        for (int d = 0; d < 6; ++d) a6[d] = qb[obase + d];
        for (int c = 0; c < 96; ++c) {
            float xv = xw[c][l];
#pragma unroll
            for (int d = 0; d < 6; ++d) a6[d] += qw[(obase + d) * C_ + c] * xv;
        }
#pragma unroll
        for (int d = 0; d < 6; ++d) qkvh[w][d][l] = a6[d];
        __syncthreads();

        if (tid < 36) {
            int d = tid / 6, e = tid - d * 6;
            float s = 0.f;
            for (int p = 0; p < 64; ++p) s += qkvh[0][d][p] * qkvh[1][e][p];
            sraw[d][e] = s * scale;
        }
        __syncthreads();

        if (tid < 6) {
            float m = sraw[tid][0];
#pragma unroll
            for (int e = 1; e < 6; ++e) m = fmaxf(m, sraw[tid][e]);
            float ex[6], ssum = 0.f;
#pragma unroll
            for (int e = 0; e < 6; ++e) { ex[e] = __expf(sraw[tid][e] - m); ssum += ex[e]; }
            float inv = 1.f / ssum;
#pragma unroll
            for (int e = 0; e < 6; ++e) attw[tid][e] = ex[e] * inv;
        }
        __syncthreads();

        float o6[6];
#pragma unroll
        for (int d = 0; d < 6; ++d) o6[d] = 0.f;
#pragma unroll
        for (int e = 0; e < 6; ++e) {
            float vv = qkvh[2][e][l];
#pragma unroll
            for (int d = 0; d < 6; ++d) o6[d] += attw[d][e] * vv;
        }
#pragma unroll
        for (int j = 0; j < 32; ++j) {
            const float* wp2 = pw + (w * 32 + j) * C_ + h * 6;
            accp[j] += wp2[0]*o6[0] + wp2[1]*o6[1] + wp2[2]*o6[2]
                     + wp2[3]*o6[3] + wp2[4]*o6[4] + wp2[5]*o6[5];
        }
        __syncthreads();
    }

#pragma unroll
    for (int j = 0; j < 32; ++j) {
        int co = w * 32 + j;
        size_t addr = ((size_t)(b * C_ + co) * H_ + gy) * W_ + gx;
        outacc[addr] += 0.5f * (accp[j] + pb[co]);
    }
}

// ---------------------------------------------------------------------------
extern "C" void kernel_launch(void* const* d_in, const int* in_sizes, int n_in,
                              void* d_out, int out_size, void* d_ws, size_t ws_size,
                              hipStream_t stream) {
    const float* x     = (const float*)d_in[0];
    const float* t_emb = (const float*)d_in[1];
    const float* w1    = (const float*)d_in[2];
    const float* b1    = (const float*)d_in[3];
    const float* g1    = (const float*)d_in[4];
    const float* be1   = (const float*)d_in[5];
    const float* wt    = (const float*)d_in[6];
    const float* bt    = (const float*)d_in[7];
    const float* qkv_w = (const float*)d_in[8];
    const float* qkv_b = (const float*)d_in[9];
    const float* proj_w= (const float*)d_in[10];
    const float* proj_b= (const float*)d_in[11];
    const float* ga    = (const float*)d_in[12];
    const float* ba    = (const float*)d_in[13];
    const float* w2    = (const float*)d_in[14];
    const float* b2    = (const float*)d_in[15];
    const float* g2    = (const float*)d_in[16];
    const float* be2   = (const float*)d_in[17];

    float* out  = (float*)d_out;                       // also used as y1 scratch
    const size_t PLANE = (size_t)B_ * C_ * HW_;        // 25165824 elements
    float* ws0   = (float*)d_ws;                       // h (residual -> h2)
    float* ws1   = ws0 + PLANE;                        // h_gn, then y2
    float* stats = ws1 + PLANE;                        // stats1[128] stats2[128] stats3[128]
    float* tvec  = stats + 384;                        // [16][192]

    hipMemsetAsync(stats, 0, 384 * sizeof(float), stream);
    temb_kernel<<<12, 256, 0, stream>>>(t_emb, wt, bt, tvec);

    // y1 = conv3x3(x, w1, b1) -> out, stats1
    conv3x3_kernel<<<dim3(8, 8, 16), 256, 0, stream>>>(x, w1, b1, out, stats);
    // h = silu(GN(y1)) * (1+shift) + bias -> ws0, stats2
    apply1_kernel<<<B_ * C_, 256, 0, stream>>>(out, stats, g1, be1, tvec, ws0, stats + 128);
    // h_gn = GN(h; ga, ba) -> ws1
    gn_apply_kernel<<<B_ * C_, 256, 0, stream>>>(ws0, stats + 128, ga, ba, ws1, 0);
    // ws0 += 0.5*(win_attn(h_gn, shift=0)) ; ws0 += 0.5*(win_attn shifted)
    winattn_kernel<<<dim3(16, 16, 16), 192, 0, stream>>>(ws1, qkv_w, qkv_b, proj_w, proj_b, ws0, 0);
    winattn_kernel<<<dim3(16, 16, 16), 192, 0, stream>>>(ws1, qkv_w, qkv_b, proj_w, proj_b, ws0, 4);
    // y2 = conv3x3(h2, w2, b2) -> ws1, stats3
    conv3x3_kernel<<<dim3(8, 8, 16), 256, 0, stream>>>(ws0, w2, b2, ws1, stats + 256);
    // out = silu(GN(y2; g2, be2))
    gn_apply_kernel<<<B_ * C_, 256, 0, stream>>>(ws1, stats + 256, g2, be2, out, 1);
}

// Round 2
// 3503.668 us; speedup vs baseline: 2.1103x; 2.1103x over previous
//
#include <hip/hip_runtime.h>

// Problem constants
#define B_   16
#define C_   96
#define H_   128
#define W_   128
#define HW_  16384          // 128*128
#define GROUPS_ 4
#define CPG_ 24             // channels per group
#define NPG_ 393216.0f      // CPG_*HW_ elements per (batch, group)
#define TDIM_ 256
#define HEADS_ 16
#define PLANE_ ((size_t)B_ * C_ * HW_)   // 25165824 elements

typedef unsigned short ushort_t;
typedef __bf16 bf16x8 __attribute__((ext_vector_type(8)));
typedef float  f32x4  __attribute__((ext_vector_type(4)));

#define ICP 104   // padded ic stride in LDS (bf16 elems): 208B stride -> conflict-free-ish, 16B aligned

__device__ __forceinline__ float silu_f(float x) {
    return x / (1.f + __expf(-x));
}

// ---------------------------------------------------------------------------
// t = silu(t_emb @ wt.T + bt)   -> tvec[B][192]
// ---------------------------------------------------------------------------
__global__ void temb_kernel(const float* __restrict__ t_emb,
                            const float* __restrict__ wt,
                            const float* __restrict__ bt,
                            float* __restrict__ tvec) {
    int idx = blockIdx.x * 256 + threadIdx.x;   // 16*192 = 3072
    if (idx >= B_ * 192) return;
    int b = idx / 192, o = idx - b * 192;
    float a = bt[o];
    const float* te = t_emb + b * TDIM_;
    const float* wr = wt + o * TDIM_;
    for (int k = 0; k < TDIM_; ++k) a += te[k] * wr[k];
    tvec[idx] = silu_f(a);
}

// ---------------------------------------------------------------------------
// fp32 -> bf16 cast (vectorized float4 -> ushort4)
// ---------------------------------------------------------------------------
__global__ void castbf_kernel(const float* __restrict__ src,
                              ushort_t* __restrict__ dst, int n4) {
    int i = blockIdx.x * 256 + threadIdx.x;
    if (i >= n4) return;
    float4 v = ((const float4*)src)[i];
    __bf16 h0 = (__bf16)v.x, h1 = (__bf16)v.y, h2 = (__bf16)v.z, h3 = (__bf16)v.w;
    ushort4 u;
    u.x = *(ushort_t*)&h0; u.y = *(ushort_t*)&h1;
    u.z = *(ushort_t*)&h2; u.w = *(ushort_t*)&h3;
    ((ushort4*)dst)[i] = u;
}

// ---------------------------------------------------------------------------
// weight prep: w[oc][ic][3][3] fp32 -> wbf[ky*3+kx][oc][ic] bf16
// ---------------------------------------------------------------------------
__global__ void wprep_kernel(const float* __restrict__ w, ushort_t* __restrict__ wbf) {
    int idx = blockIdx.x * 256 + threadIdx.x;   // 9*96*96 = 82944
    if (idx >= 9 * 96 * 96) return;
    int ic = idx % 96;
    int t  = idx / 96;
    int oc = t % 96;
    int kk = t / 96;
    float f = w[(oc * 96 + ic) * 9 + kk];
    __bf16 h = (__bf16)f;
    wbf[idx] = *(ushort_t*)&h;
}

// ---------------------------------------------------------------------------
// conv3x3 via implicit-GEMM MFMA (bf16 in, fp32 acc) + bias + GN stats.
// Block: 2 output rows x 64 px, all 96 oc. 256 thr = 4 waves.
// Wave w: M-tiles = {row0 x=w*16, row1 x=w*16} (2), N-tiles = 6 (96 oc).
// K-loop: (ky,kx) x ic-chunks of 32 -> 27 MFMA k-steps.
// LDS: input [4 rows][66 x][ICP ic] bf16 + weight slice [96 oc][ICP ic] bf16.
// ---------------------------------------------------------------------------
__global__ __launch_bounds__(256, 2)
void conv3x3_mfma_kernel(const ushort_t* __restrict__ xbf,   // [B][96][128][128] bf16
                         const ushort_t* __restrict__ wbf,   // [9][96][96] bf16
                         const float* __restrict__ bias,
                         float* __restrict__ out,            // [B][96][128][128] fp32
                         float* __restrict__ stats /* [B][4][2] */) {
    __shared__ __align__(16) ushort_t ti[4 * 66 * ICP];   // 54912 B
    __shared__ __align__(16) ushort_t wc[96 * ICP];       // 19968 B
    __shared__ float red[4][96][2];                       // 3072 B

    const int b   = blockIdx.z;
    const int y0  = blockIdx.y * 2;
    const int x0  = blockIdx.x * 64;
    const int tid = threadIdx.x;
    const int w    = tid >> 6;
    const int lane = tid & 63;
    const int l15  = lane & 15;
    const int quad = lane >> 4;

    // ---- stage input tile: rows y0-1..y0+2, x0-1..x0+64, all 96 ic (zero pad)
    for (int idx = tid; idx < 4 * 96 * 66; idx += 256) {   // 99 iters exact
        int xi = idx % 66;
        int t2 = idx / 66;
        int ic = t2 % 96;
        int r  = t2 / 96;
        int gy = y0 - 1 + r, gx = x0 - 1 + xi;
        ushort_t v = 0;
        if (gy >= 0 && gy < H_ && gx >= 0 && gx < W_)
            v = xbf[((b * 96 + ic) * H_ + gy) * W_ + gx];
        ti[(r * 66 + xi) * ICP + ic] = v;
    }

    f32x4 acc[2][6];
#pragma unroll
    for (int m = 0; m < 2; ++m)
#pragma unroll
        for (int nt = 0; nt < 6; ++nt)
            acc[m][nt] = (f32x4){0.f, 0.f, 0.f, 0.f};

    for (int kk = 0; kk < 9; ++kk) {
        const int ky = kk / 3, kx = kk - ky * 3;
        __syncthreads();   // prior wc consumers done (and ti staged, first iter)
        const ushort_t* wsrc = wbf + kk * 96 * 96;
        for (int idx = tid; idx < 96 * 96; idx += 256) {   // 36 iters exact
            int ic = idx % 96;
            int oc = idx / 96;
            wc[oc * ICP + ic] = wsrc[idx];
        }
        __syncthreads();
#pragma unroll 1
        for (int ck = 0; ck < 3; ++ck) {
            const int kbase = ck * 32 + quad * 8;
            bf16x8 a0 = *(const bf16x8*)&ti[((0 + ky) * 66 + (w * 16 + l15 + kx)) * ICP + kbase];
            bf16x8 a1 = *(const bf16x8*)&ti[((1 + ky) * 66 + (w * 16 + l15 + kx)) * ICP + kbase];
#pragma unroll
            for (int nt = 0; nt < 6; ++nt) {
                bf16x8 bv = *(const bf16x8*)&wc[(nt * 16 + l15) * ICP + kbase];
                acc[0][nt] = __builtin_amdgcn_mfma_f32_16x16x32_bf16(a0, bv, acc[0][nt], 0, 0, 0);
                acc[1][nt] = __builtin_amdgcn_mfma_f32_16x16x32_bf16(a1, bv, acc[1][nt], 0, 0, 0);
            }
        }
    }

    // ---- epilogue: bias add, store, GN stats
    float lsum[6], lsq[6];
#pragma unroll
    for (int nt = 0; nt < 6; ++nt) { lsum[nt] = 0.f; lsq[nt] = 0.f; }

#pragma unroll
    for (int m = 0; m < 2; ++m) {
        const int gy = y0 + m;
        const int gx = x0 + w * 16 + quad * 4;
#pragma unroll
        for (int nt = 0; nt < 6; ++nt) {
            const int oc = nt * 16 + l15;
            const float bz = bias[oc];
            float4 vv;
            float v0 = acc[m][nt][0] + bz;
            float v1 = acc[m][nt][1] + bz;
            float v2 = acc[m][nt][2] + bz;
            float v3 = acc[m][nt][3] + bz;
            vv.x = v0; vv.y = v1; vv.z = v2; vv.w = v3;
            *(float4*)&out[((b * 96 + oc) * H_ + gy) * W_ + gx] = vv;
            lsum[nt] += v0 + v1 + v2 + v3;
            lsq[nt]  += v0 * v0 + v1 * v1 + v2 * v2 + v3 * v3;
        }
    }
    // reduce across quads (lanes with equal l15 share oc)
#pragma unroll
    for (int nt = 0; nt < 6; ++nt) {
        float s = lsum[nt], q = lsq[nt];
        s += __shfl_down(s, 32, 64);
        s += __shfl_down(s, 16, 64);
        q += __shfl_down(q, 32, 64);
        q += __shfl_down(q, 16, 64);
        if (lane < 16) {
            red[w][nt * 16 + lane][0] = s;
            red[w][nt * 16 + lane][1] = q;
        }
    }
    __syncthreads();
    if (tid < 8) {
        const int g = tid >> 1, which = tid & 1;
        float v = 0.f;
        for (int oc = g * CPG_; oc < g * CPG_ + CPG_; ++oc)
            for (int wv = 0; wv < 4; ++wv) v += red[wv][oc][which];
        atomicAdd(&stats[(b * 4 + g) * 2 + which], v);
    }
}

// ---------------------------------------------------------------------------
// h = silu(GN(y; stats1, g1, be1)) * (1 + shift[b,c]) + bias[b,c]
// emits h and accumulates stats2 (sum/sumsq of h per (b,group)).
// ---------------------------------------------------------------------------
__global__ void apply1_kernel(const float* __restrict__ y,
                              const float* __restrict__ stats1,
                              const float* __restrict__ g1,
                              const float* __restrict__ be1,
                              const float* __restrict__ tvec,
                              float* __restrict__ h,
                              float* __restrict__ stats2) {
    const int bc = blockIdx.x;
    const int b = bc / C_, c = bc - b * C_;
    const int g = c / CPG_;
    const float sum = stats1[(b * 4 + g) * 2], sumsq = stats1[(b * 4 + g) * 2 + 1];
    const float mean = sum / NPG_;
    const float var  = sumsq / NPG_ - mean * mean;
    const float rstd = rsqrtf(var + 1e-5f);
    const float sc = rstd * g1[c];
    const float sh = be1[c] - mean * sc;
    const float tsc = 1.f + tvec[b * 192 + c];
    const float tbi = tvec[b * 192 + 96 + c];

    const float4* yp = (const float4*)(y + (size_t)bc * HW_);
    float4* hp = (float4*)(h + (size_t)bc * HW_);
    float ls = 0.f, lss = 0.f;
    for (int i = threadIdx.x; i < HW_ / 4; i += 256) {
        float4 v = yp[i];
        float r0 = silu_f(v.x * sc + sh) * tsc + tbi;
        float r1 = silu_f(v.y * sc + sh) * tsc + tbi;
        float r2 = silu_f(v.z * sc + sh) * tsc + tbi;
        float r3 = silu_f(v.w * sc + sh) * tsc + tbi;
        hp[i] = make_float4(r0, r1, r2, r3);
        ls  += r0 + r1 + r2 + r3;
        lss += r0*r0 + r1*r1 + r2*r2 + r3*r3;
    }
    for (int off = 32; off > 0; off >>= 1) {
        ls  += __shfl_down(ls, off, 64);
        lss += __shfl_down(lss, off, 64);
    }
    if ((threadIdx.x & 63) == 0) {
        atomicAdd(&stats2[(b * 4 + g) * 2 + 0], ls);
        atomicAdd(&stats2[(b * 4 + g) * 2 + 1], lss);
    }
}

// ---------------------------------------------------------------------------
// out = GN(in; stats, gamma, beta), optional silu.
// ---------------------------------------------------------------------------
__global__ void gn_apply_kernel(const float* __restrict__ in,
                                const float* __restrict__ stats,
                                const float* __restrict__ gamma,
                                const float* __restrict__ beta,
                                float* __restrict__ out, int dosilu) {
    const int bc = blockIdx.x;
    const int b = bc / C_, c = bc - b * C_;
    const int g = c / CPG_;
    const float sum = stats[(b * 4 + g) * 2], sumsq = stats[(b * 4 + g) * 2 + 1];
    const float mean = sum / NPG_;
    const float var  = sumsq / NPG_ - mean * mean;
    const float rstd = rsqrtf(var + 1e-5f);
    const float sc = rstd * gamma[c];
    const float sh = beta[c] - mean * sc;
    const float4* ip = (const float4*)(in + (size_t)bc * HW_);
    float4* op = (float4*)(out + (size_t)bc * HW_);
    for (int i = threadIdx.x; i < HW_ / 4; i += 256) {
        float4 v = ip[i];
        float r0 = v.x * sc + sh, r1 = v.y * sc + sh;
        float r2 = v.z * sc + sh, r3 = v.w * sc + sh;
        if (dosilu) { r0 = silu_f(r0); r1 = silu_f(r1); r2 = silu_f(r2); r3 = silu_f(r3); }
        op[i] = make_float4(r0, r1, r2, r3);
    }
}

// ---------------------------------------------------------------------------
// Fused window attention (unchanged from R1; next round's target).
// ---------------------------------------------------------------------------
__global__ __launch_bounds__(192, 2)
void winattn_kernel(const float* __restrict__ xin,
                    const float* __restrict__ qw, const float* __restrict__ qb,
                    const float* __restrict__ pw, const float* __restrict__ pb,
                    float* __restrict__ outacc, int shift) {
    __shared__ float xw[96][64];
    __shared__ float qkvh[3][6][64];
    __shared__ float sraw[6][6];
    __shared__ float attw[6][6];

    const int b = blockIdx.z, wi = blockIdx.y, wj = blockIdx.x;
    const int tid = threadIdx.x;
    const int w = tid >> 6, l = tid & 63;
    const int r = l >> 3, cc = l & 7;
    const int gy = (wi * 8 + r + shift) & 127;
    const int gx = (wj * 8 + cc + shift) & 127;

    for (int ch = w; ch < 96; ch += 3)
        xw[ch][l] = xin[((b * C_ + ch) * H_ + gy) * W_ + gx];

    float accp[32];
#pragma unroll
    for (int j = 0; j < 32; ++j) accp[j] = 0.f;
    __syncthreads();

    const float scale = 0.40824829046386302f;  // 6^{-1/2}

    for (int h = 0; h < HEADS_; ++h) {
        const int obase = w * 96 + h * 6;
        float a6[6];
#pragma unroll
        for (int d = 0; d < 6; ++d) a6[d] = qb[obase + d];
        for (int c = 0; c < 96; ++c) {
            float xv = xw[c][l];
#pragma unroll
            for (int d = 0; d < 6; ++d) a6[d] += qw[(obase + d) * C_ + c] * xv;
        }
#pragma unroll
        for (int d = 0; d < 6; ++d) qkvh[w][d][l] = a6[d];
        __syncthreads();

        if (tid < 36) {
            int d = tid / 6, e = tid - d * 6;
            float s = 0.f;
            for (int p = 0; p < 64; ++p) s += qkvh[0][d][p] * qkvh[1][e][p];
            sraw[d][e] = s * scale;
        }
        __syncthreads();

        if (tid < 6) {
            float m = sraw[tid][0];
#pragma unroll
            for (int e = 1; e < 6; ++e) m = fmaxf(m, sraw[tid][e]);
            float ex[6], ssum = 0.f;
#pragma unroll
            for (int e = 0; e < 6; ++e) { ex[e] = __expf(sraw[tid][e] - m); ssum += ex[e]; }
            float inv = 1.f / ssum;
#pragma unroll
            for (int e = 0; e < 6; ++e) attw[tid][e] = ex[e] * inv;
        }
        __syncthreads();

        float o6[6];
#pragma unroll
        for (int d = 0; d < 6; ++d) o6[d] = 0.f;
#pragma unroll
        for (int e = 0; e < 6; ++e) {
            float vv = qkvh[2][e][l];
#pragma unroll
            for (int d = 0; d < 6; ++d) o6[d] += attw[d][e] * vv;
        }
#pragma unroll
        for (int j = 0; j < 32; ++j) {
            const float* wp2 = pw + (w * 32 + j) * C_ + h * 6;
            accp[j] += wp2[0]*o6[0] + wp2[1]*o6[1] + wp2[2]*o6[2]
                     + wp2[3]*o6[3] + wp2[4]*o6[4] + wp2[5]*o6[5];
        }
        __syncthreads();
    }

#pragma unroll
    for (int j = 0; j < 32; ++j) {
        int co = w * 32 + j;
        size_t addr = ((size_t)(b * C_ + co) * H_ + gy) * W_ + gx;
        outacc[addr] += 0.5f * (accp[j] + pb[co]);
    }
}

// ---------------------------------------------------------------------------
extern "C" void kernel_launch(void* const* d_in, const int* in_sizes, int n_in,
                              void* d_out, int out_size, void* d_ws, size_t ws_size,
                              hipStream_t stream) {
    const float* x     = (const float*)d_in[0];
    const float* t_emb = (const float*)d_in[1];
    const float* w1    = (const float*)d_in[2];
    const float* b1    = (const float*)d_in[3];
    const float* g1    = (const float*)d_in[4];
    const float* be1   = (const float*)d_in[5];
    const float* wt    = (const float*)d_in[6];
    const float* bt    = (const float*)d_in[7];
    const float* qkv_w = (const float*)d_in[8];
    const float* qkv_b = (const float*)d_in[9];
    const float* proj_w= (const float*)d_in[10];
    const float* proj_b= (const float*)d_in[11];
    const float* ga    = (const float*)d_in[12];
    const float* ba    = (const float*)d_in[13];
    const float* w2    = (const float*)d_in[14];
    const float* b2    = (const float*)d_in[15];
    const float* g2    = (const float*)d_in[16];
    const float* be2   = (const float*)d_in[17];

    float* out  = (float*)d_out;
    float* ws0  = (float*)d_ws;            // phase A: wbf1 scratch; phase B: h / h2
    float* ws1  = ws0 + PLANE_;            // phase A: xbf1; then h_gn; then y2
    float* stats = ws1 + PLANE_;           // stats1[128] stats2[128] stats3[128]
    float* tvec  = stats + 384;            // [16][192]

    // bf16 scratch aliases (dead-phase reuse; no extra ws needed)
    ushort_t* wbf1 = (ushort_t*)ws0;               // dead once apply1 writes h
    ushort_t* xbf1 = (ushort_t*)ws1;               // dead once gn_apply writes h_gn
    ushort_t* xbf2 = (ushort_t*)out;               // y1 dead after apply1
    ushort_t* wbf2 = (ushort_t*)out + PLANE_;      // second half of d_out

    hipMemsetAsync(stats, 0, 384 * sizeof(float), stream);
    temb_kernel<<<12, 256, 0, stream>>>(t_emb, wt, bt, tvec);

    // --- conv1: cast + wprep + MFMA conv (y1 -> d_out, stats1)
    wprep_kernel<<<(9*96*96 + 255)/256, 256, 0, stream>>>(w1, wbf1);
    castbf_kernel<<<(int)(PLANE_/4/256), 256, 0, stream>>>(x, xbf1, (int)(PLANE_/4));
    conv3x3_mfma_kernel<<<dim3(2, 64, 16), 256, 0, stream>>>(xbf1, wbf1, b1, out, stats);

    // h = silu(GN(y1)) * (1+shift) + bias -> ws0, stats2
    apply1_kernel<<<B_ * C_, 256, 0, stream>>>(out, stats, g1, be1, tvec, ws0, stats + 128);
    // h_gn = GN(h; ga, ba) -> ws1
    gn_apply_kernel<<<B_ * C_, 256, 0, stream>>>(ws0, stats + 128, ga, ba, ws1, 0);
    // ws0 += 0.5*win_attn(h_gn, shift 0 and 4)
    winattn_kernel<<<dim3(16, 16, 16), 192, 0, stream>>>(ws1, qkv_w, qkv_b, proj_w, proj_b, ws0, 0);
    winattn_kernel<<<dim3(16, 16, 16), 192, 0, stream>>>(ws1, qkv_w, qkv_b, proj_w, proj_b, ws0, 4);

    // --- conv2: cast + wprep + MFMA conv (y2 -> ws1, stats3)
    wprep_kernel<<<(9*96*96 + 255)/256, 256, 0, stream>>>(w2, wbf2);
    castbf_kernel<<<(int)(PLANE_/4/256), 256, 0, stream>>>(ws0, xbf2, (int)(PLANE_/4));
    conv3x3_mfma_kernel<<<dim3(2, 64, 16), 256, 0, stream>>>(xbf2, wbf2, b2, ws1, stats + 256);

    // out = silu(GN(y2; g2, be2))
    gn_apply_kernel<<<B_ * C_, 256, 0, stream>>>(ws1, stats + 256, g2, be2, out, 1);
}

// Round 3
// 2164.771 us; speedup vs baseline: 3.4155x; 1.6185x over previous
//
#include <hip/hip_runtime.h>

// Problem constants
#define B_   16
#define C_   96
#define H_   128
#define W_   128
#define HW_  16384
#define CPG_ 24
#define NPG_ 393216.0f
#define TDIM_ 256
#define PLANE_ ((size_t)B_ * C_ * HW_)   // 25165824

typedef unsigned short ushort_t;
typedef __bf16 bf16x8 __attribute__((ext_vector_type(8)));
typedef float  f32x4  __attribute__((ext_vector_type(4)));

#define ICP 104   // padded K-stride in LDS (bf16 elems), 16B-aligned rows

__device__ __forceinline__ float silu_f(float x) { return x / (1.f + __expf(-x)); }
__device__ __forceinline__ float bf2f(ushort_t u) {
    union { float f; unsigned int i; } x; x.i = ((unsigned int)u) << 16; return x.f;
}
__device__ __forceinline__ ushort_t f2bf(float f) {
    __bf16 h = (__bf16)f; return *(ushort_t*)&h;
}

// ---------------------------------------------------------------------------
// t = silu(t_emb @ wt.T + bt) -> tvec[B][192]
// ---------------------------------------------------------------------------
__global__ void temb_kernel(const float* __restrict__ t_emb,
                            const float* __restrict__ wt,
                            const float* __restrict__ bt,
                            float* __restrict__ tvec) {
    int idx = blockIdx.x * 256 + threadIdx.x;
    if (idx >= B_ * 192) return;
    int b = idx / 192, o = idx - b * 192;
    float a = bt[o];
    const float* te = t_emb + b * TDIM_;
    const float* wr = wt + o * TDIM_;
    for (int k = 0; k < TDIM_; ++k) a += te[k] * wr[k];
    tvec[idx] = silu_f(a);
}

// ---------------------------------------------------------------------------
// fp32 -> bf16 cast
// ---------------------------------------------------------------------------
__global__ void castbf_kernel(const float* __restrict__ src,
                              ushort_t* __restrict__ dst, int n4) {
    int i = blockIdx.x * 256 + threadIdx.x;
    if (i >= n4) return;
    float4 v = ((const float4*)src)[i];
    ushort4 u = { f2bf(v.x), f2bf(v.y), f2bf(v.z), f2bf(v.w) };
    ((ushort4*)dst)[i] = u;
}

// ---------------------------------------------------------------------------
// conv3x3 implicit-GEMM MFMA (bf16 in, fp32 w cast in staging) + bias + GN stats
// ---------------------------------------------------------------------------
__global__ __launch_bounds__(256, 2)
void conv3x3_mfma_kernel(const ushort_t* __restrict__ xbf,
                         const float* __restrict__ w,     // [oc][ic][3][3] fp32
                         const float* __restrict__ bias,
                         float* __restrict__ out,
                         float* __restrict__ stats) {
    __shared__ __align__(16) ushort_t ti[4 * 66 * ICP];
    __shared__ __align__(16) ushort_t wc[96 * ICP];
    __shared__ float red[4][96][2];

    const int b   = blockIdx.z;
    const int y0  = blockIdx.y * 2;
    const int x0  = blockIdx.x * 64;
    const int tid = threadIdx.x;
    const int wv   = tid >> 6;
    const int lane = tid & 63;
    const int l15  = lane & 15;
    const int quad = lane >> 4;

    for (int idx = tid; idx < 4 * 96 * 66; idx += 256) {
        int xi = idx % 66;
        int t2 = idx / 66;
        int ic = t2 % 96;
        int r  = t2 / 96;
        int gy = y0 - 1 + r, gx = x0 - 1 + xi;
        ushort_t v = 0;
        if (gy >= 0 && gy < H_ && gx >= 0 && gx < W_)
            v = xbf[((b * 96 + ic) * H_ + gy) * W_ + gx];
        ti[(r * 66 + xi) * ICP + ic] = v;
    }

    f32x4 acc[2][6];
#pragma unroll
    for (int m = 0; m < 2; ++m)
#pragma unroll
        for (int nt = 0; nt < 6; ++nt)
            acc[m][nt] = (f32x4){0.f, 0.f, 0.f, 0.f};

    for (int kk = 0; kk < 9; ++kk) {
        const int ky = kk / 3, kx = kk - ky * 3;
        __syncthreads();
        for (int idx = tid; idx < 96 * 96; idx += 256) {
            int ic = idx % 96;
            int oc = idx / 96;
            wc[oc * ICP + ic] = f2bf(w[(oc * 96 + ic) * 9 + kk]);
        }
        __syncthreads();
#pragma unroll 1
        for (int ck = 0; ck < 3; ++ck) {
            const int kbase = ck * 32 + quad * 8;
            bf16x8 a0 = *(const bf16x8*)&ti[((0 + ky) * 66 + (wv * 16 + l15 + kx)) * ICP + kbase];
            bf16x8 a1 = *(const bf16x8*)&ti[((1 + ky) * 66 + (wv * 16 + l15 + kx)) * ICP + kbase];
#pragma unroll
            for (int nt = 0; nt < 6; ++nt) {
                bf16x8 bv = *(const bf16x8*)&wc[(nt * 16 + l15) * ICP + kbase];
                acc[0][nt] = __builtin_amdgcn_mfma_f32_16x16x32_bf16(a0, bv, acc[0][nt], 0, 0, 0);
                acc[1][nt] = __builtin_amdgcn_mfma_f32_16x16x32_bf16(a1, bv, acc[1][nt], 0, 0, 0);
            }
        }
    }

    float lsum[6], lsq[6];
#pragma unroll
    for (int nt = 0; nt < 6; ++nt) { lsum[nt] = 0.f; lsq[nt] = 0.f; }

#pragma unroll
    for (int m = 0; m < 2; ++m) {
        const int gy = y0 + m;
        const int gx = x0 + wv * 16 + quad * 4;
#pragma unroll
        for (int nt = 0; nt < 6; ++nt) {
            const int oc = nt * 16 + l15;
            const float bz = bias[oc];
            float v0 = acc[m][nt][0] + bz;
            float v1 = acc[m][nt][1] + bz;
            float v2 = acc[m][nt][2] + bz;
            float v3 = acc[m][nt][3] + bz;
            float4 vv = make_float4(v0, v1, v2, v3);
            *(float4*)&out[((b * 96 + oc) * H_ + gy) * W_ + gx] = vv;
            lsum[nt] += v0 + v1 + v2 + v3;
            lsq[nt]  += v0 * v0 + v1 * v1 + v2 * v2 + v3 * v3;
        }
    }
#pragma unroll
    for (int nt = 0; nt < 6; ++nt) {
        float s = lsum[nt], q = lsq[nt];
        s += __shfl_down(s, 32, 64);
        s += __shfl_down(s, 16, 64);
        q += __shfl_down(q, 32, 64);
        q += __shfl_down(q, 16, 64);
        if (lane < 16) {
            red[wv][nt * 16 + lane][0] = s;
            red[wv][nt * 16 + lane][1] = q;
        }
    }
    __syncthreads();
    if (tid < 8) {
        const int g = tid >> 1, which = tid & 1;
        float v = 0.f;
        for (int oc = g * CPG_; oc < g * CPG_ + CPG_; ++oc)
            for (int w2 = 0; w2 < 4; ++w2) v += red[w2][oc][which];
        atomicAdd(&stats[(b * 4 + g) * 2 + which], v);
    }
}

// ---------------------------------------------------------------------------
// h = silu(GN(y)) * (1+shift) + bias  (IN-PLACE on d_out), emits stats2
// ---------------------------------------------------------------------------
__global__ void apply1_kernel(const float* y,
                              const float* __restrict__ stats1,
                              const float* __restrict__ g1,
                              const float* __restrict__ be1,
                              const float* __restrict__ tvec,
                              float* h,
                              float* __restrict__ stats2) {
    const int bc = blockIdx.x;
    const int b = bc / C_, c = bc - b * C_;
    const int g = c / CPG_;
    const float sum = stats1[(b * 4 + g) * 2], sumsq = stats1[(b * 4 + g) * 2 + 1];
    const float mean = sum / NPG_;
    const float var  = sumsq / NPG_ - mean * mean;
    const float rstd = rsqrtf(var + 1e-5f);
    const float sc = rstd * g1[c];
    const float sh = be1[c] - mean * sc;
    const float tsc = 1.f + tvec[b * 192 + c];
    const float tbi = tvec[b * 192 + 96 + c];

    const float4* yp = (const float4*)(y + (size_t)bc * HW_);
    float4* hp = (float4*)(h + (size_t)bc * HW_);
    float ls = 0.f, lss = 0.f;
    for (int i = threadIdx.x; i < HW_ / 4; i += 256) {
        float4 v = yp[i];
        float r0 = silu_f(v.x * sc + sh) * tsc + tbi;
        float r1 = silu_f(v.y * sc + sh) * tsc + tbi;
        float r2 = silu_f(v.z * sc + sh) * tsc + tbi;
        float r3 = silu_f(v.w * sc + sh) * tsc + tbi;
        hp[i] = make_float4(r0, r1, r2, r3);
        ls  += r0 + r1 + r2 + r3;
        lss += r0*r0 + r1*r1 + r2*r2 + r3*r3;
    }
    for (int off = 32; off > 0; off >>= 1) {
        ls  += __shfl_down(ls, off, 64);
        lss += __shfl_down(lss, off, 64);
    }
    if ((threadIdx.x & 63) == 0) {
        atomicAdd(&stats2[(b * 4 + g) * 2 + 0], ls);
        atomicAdd(&stats2[(b * 4 + g) * 2 + 1], lss);
    }
}

// ---------------------------------------------------------------------------
// GN apply -> bf16 output (qkv GEMM input)
// ---------------------------------------------------------------------------
__global__ void gn_bf16_kernel(const float* __restrict__ in,
                               const float* __restrict__ stats,
                               const float* __restrict__ gamma,
                               const float* __restrict__ beta,
                               ushort_t* __restrict__ outb) {
    const int bc = blockIdx.x;
    const int b = bc / C_, c = bc - b * C_;
    const int g = c / CPG_;
    const float sum = stats[(b * 4 + g) * 2], sumsq = stats[(b * 4 + g) * 2 + 1];
    const float mean = sum / NPG_;
    const float var  = sumsq / NPG_ - mean * mean;
    const float rstd = rsqrtf(var + 1e-5f);
    const float sc = rstd * gamma[c];
    const float sh = beta[c] - mean * sc;
    const float4* ip = (const float4*)(in + (size_t)bc * HW_);
    ushort4* op = (ushort4*)(outb + (size_t)bc * HW_);
    for (int i = threadIdx.x; i < HW_ / 4; i += 256) {
        float4 v = ip[i];
        ushort4 u = { f2bf(v.x * sc + sh), f2bf(v.y * sc + sh),
                      f2bf(v.z * sc + sh), f2bf(v.w * sc + sh) };
        op[i] = u;
    }
}

// ---------------------------------------------------------------------------
// GN apply fp32 (+silu), in-place capable
// ---------------------------------------------------------------------------
__global__ void gn_apply_kernel(const float* in,
                                const float* __restrict__ stats,
                                const float* __restrict__ gamma,
                                const float* __restrict__ beta,
                                float* out, int dosilu) {
    const int bc = blockIdx.x;
    const int b = bc / C_, c = bc - b * C_;
    const int g = c / CPG_;
    const float sum = stats[(b * 4 + g) * 2], sumsq = stats[(b * 4 + g) * 2 + 1];
    const float mean = sum / NPG_;
    const float var  = sumsq / NPG_ - mean * mean;
    const float rstd = rsqrtf(var + 1e-5f);
    const float sc = rstd * gamma[c];
    const float sh = beta[c] - mean * sc;
    const float4* ip = (const float4*)(in + (size_t)bc * HW_);
    float4* op = (float4*)(out + (size_t)bc * HW_);
    for (int i = threadIdx.x; i < HW_ / 4; i += 256) {
        float4 v = ip[i];
        float r0 = v.x * sc + sh, r1 = v.y * sc + sh;
        float r2 = v.z * sc + sh, r3 = v.w * sc + sh;
        if (dosilu) { r0 = silu_f(r0); r1 = silu_f(r1); r2 = silu_f(r2); r3 = silu_f(r3); }
        op[i] = make_float4(r0, r1, r2, r3);
    }
}

// ---------------------------------------------------------------------------
// qkv 1x1 GEMM: out plane ocg = s*96+oc, bf16. Block: 2 rows x 64 px, 96 oc.
// grid (2, 64, 48): z = b*3+s
// ---------------------------------------------------------------------------
__global__ __launch_bounds__(256, 3)
void qkv_gemm_kernel(const ushort_t* __restrict__ xq,
                     const float* __restrict__ qw,   // [288][96]
                     const float* __restrict__ qb,
                     ushort_t* __restrict__ qkvbuf) {
    __shared__ __align__(16) ushort_t ti[2 * 64 * ICP];
    __shared__ __align__(16) ushort_t wc[96 * ICP];

    const int bz = blockIdx.z;
    const int b = bz / 3, s = bz - b * 3;
    const int y0 = blockIdx.y * 2;
    const int x0 = blockIdx.x * 64;
    const int tid = threadIdx.x;
    const int wv = tid >> 6, lane = tid & 63;
    const int l15 = lane & 15, quad = lane >> 4;

    for (int idx = tid; idx < 2 * 96 * 64; idx += 256) {
        int xi = idx % 64;
        int t2 = idx / 64;
        int ic = t2 % 96;
        int r  = t2 / 96;
        ti[(r * 64 + xi) * ICP + ic] = xq[((b * 96 + ic) * H_ + y0 + r) * W_ + x0 + xi];
    }
    for (int idx = tid; idx < 96 * 96; idx += 256) {
        int ic = idx % 96;
        int oc = idx / 96;
        wc[oc * ICP + ic] = f2bf(qw[(s * 96 + oc) * 96 + ic]);
    }
    __syncthreads();

    f32x4 acc[2][6];
#pragma unroll
    for (int m = 0; m < 2; ++m)
#pragma unroll
        for (int nt = 0; nt < 6; ++nt) acc[m][nt] = (f32x4){0.f, 0.f, 0.f, 0.f};

#pragma unroll
    for (int ck = 0; ck < 3; ++ck) {
        const int kbase = ck * 32 + quad * 8;
        bf16x8 a0 = *(const bf16x8*)&ti[(0 * 64 + wv * 16 + l15) * ICP + kbase];
        bf16x8 a1 = *(const bf16x8*)&ti[(1 * 64 + wv * 16 + l15) * ICP + kbase];
#pragma unroll
        for (int nt = 0; nt < 6; ++nt) {
            bf16x8 bv = *(const bf16x8*)&wc[(nt * 16 + l15) * ICP + kbase];
            acc[0][nt] = __builtin_amdgcn_mfma_f32_16x16x32_bf16(a0, bv, acc[0][nt], 0, 0, 0);
            acc[1][nt] = __builtin_amdgcn_mfma_f32_16x16x32_bf16(a1, bv, acc[1][nt], 0, 0, 0);
        }
    }

#pragma unroll
    for (int m = 0; m < 2; ++m) {
        const int gy = y0 + m;
        const int gx = x0 + wv * 16 + quad * 4;
#pragma unroll
        for (int nt = 0; nt < 6; ++nt) {
            const int ocg = s * 96 + nt * 16 + l15;
            const float bz2 = qb[ocg];
            ushort4 u = { f2bf(acc[m][nt][0] + bz2), f2bf(acc[m][nt][1] + bz2),
                          f2bf(acc[m][nt][2] + bz2), f2bf(acc[m][nt][3] + bz2) };
            *(ushort4*)&qkvbuf[((size_t)(b * 288 + ocg) * H_ + gy) * W_ + gx] = u;
        }
    }
}

// ---------------------------------------------------------------------------
// window row loader: 8 px of plane ch, window (wy,wx) row r, with shift
// ---------------------------------------------------------------------------
__device__ __forceinline__ bf16x8 load_row(const ushort_t* __restrict__ qkv,
                                           int b, int ch, int wy, int wx,
                                           int r, int shift) {
    int gy = (wy * 8 + r + shift) & 127;
    size_t base = ((size_t)(b * 288 + ch) * H_ + gy) * W_;
    if (shift == 0) {
        return *(const bf16x8*)&qkv[base + wx * 8];
    } else {
        union { bf16x8 v; ushort4 u[2]; } t;
        t.u[0] = *(const ushort4*)&qkv[base + wx * 8 + 4];
        t.u[1] = *(const ushort4*)&qkv[base + ((wx * 8 + 8) & 127)];
        return t.v;
    }
}

// ---------------------------------------------------------------------------
// Attention core: per (b, window), 16 heads (4 per wave).
// S^T = mfma(K,Q); softmax over e in-register (cross-quad shfl_xor);
// O^T = mfma(V^T from LDS, P). shift4 pass accumulates 0.5*(O0+O4) into obuf.
// ---------------------------------------------------------------------------
__global__ __launch_bounds__(256, 4)
void attn_kernel(const ushort_t* __restrict__ qkv,
                 ushort_t* __restrict__ obuf, int shift, int accumulate) {
    __shared__ __align__(16) ushort_t vt[16 * 64 * 8 + 64];   // [h][px][8], slots 6,7 = 0

    const int b = blockIdx.z, wy = blockIdx.y, wx = blockIdx.x;
    const int tid = threadIdx.x;
    const int wv = tid >> 6, lane = tid & 63;
    const int l15 = lane & 15, quad = lane >> 4;

    // zero vt
    for (int i = tid; i < (16 * 64 * 8 + 64) / 2; i += 256) ((unsigned int*)vt)[i] = 0;
    __syncthreads();
    // fill V^T
    {
        const int px = tid & 63;
        const int r = px >> 3, c8 = px & 7;
        const int gy = (wy * 8 + r + shift) & 127;
        const int gx = (wx * 8 + c8 + shift) & 127;
        for (int cc = tid >> 6; cc < 96; cc += 4) {
            ushort_t v = qkv[((size_t)(b * 288 + 192 + cc) * H_ + gy) * W_ + gx];
            int hh = cc / 6, slot = cc - hh * 6;
            vt[(hh * 64 + px) * 8 + slot] = v;
        }
    }
    __syncthreads();

    const float scale = 0.40824829046386302f;  // 6^-0.5

    for (int i = 0; i < 4; ++i) {
        const int h = wv * 4 + i;
        // ---- S^T = K Q^T  (m=e, n=d, k=px)
        f32x4 sa = (f32x4){0.f, 0.f, 0.f, 0.f};
#pragma unroll
        for (int ck = 0; ck < 2; ++ck) {
            bf16x8 af = load_row(qkv, b, 96 + h * 6 + l15, wy, wx, ck * 4 + quad, shift);
            bf16x8 bfv = load_row(qkv, b, h * 6 + l15, wy, wx, ck * 4 + quad, shift);
            sa = __builtin_amdgcn_mfma_f32_16x16x32_bf16(af, bfv, sa, 0, 0, 0);
        }
        // lane holds S^T[e=quad*4+reg][d=l15]; valid: quad0 regs0-3, quad1 regs0-1
        float s0 = sa[0] * scale, s1 = sa[1] * scale, s2 = sa[2] * scale, s3 = sa[3] * scale;
        float m = -3.4e38f;
        if (quad == 0) m = fmaxf(fmaxf(s0, s1), fmaxf(s2, s3));
        else if (quad == 1) m = fmaxf(s0, s1);
        m = fmaxf(m, __shfl_xor(m, 16, 64));
        m = fmaxf(m, __shfl_xor(m, 32, 64));
        float p0 = (quad <= 1) ? __expf(s0 - m) : 0.f;
        float p1 = (quad <= 1) ? __expf(s1 - m) : 0.f;
        float p2 = (quad == 0) ? __expf(s2 - m) : 0.f;
        float p3 = (quad == 0) ? __expf(s3 - m) : 0.f;
        float sum = p0 + p1 + p2 + p3;
        sum += __shfl_xor(sum, 16, 64);
        sum += __shfl_xor(sum, 32, 64);
        float inv = 1.f / sum;
        p0 *= inv; p1 *= inv; p2 *= inv; p3 *= inv;
        // ---- build P B-frag: B[n=d=l15][k=e=quad*8+j]; only quad0 nonzero
        float e4 = __shfl_xor(p0, 16, 64);   // quad0 receives P[d][4]
        float e5 = __shfl_xor(p1, 16, 64);   // quad0 receives P[d][5]
        bf16x8 pf;
        pf[0] = (__bf16)p0; pf[1] = (__bf16)p1; pf[2] = (__bf16)p2; pf[3] = (__bf16)p3;
        pf[4] = (__bf16)e4; pf[5] = (__bf16)e5;
        pf[6] = (__bf16)0.f; pf[7] = (__bf16)0.f;
        if (quad != 0) {
            bf16x8 z = {};
            pf = z;
        }
        // ---- O^T tiles: m=px (4 tiles), n=d
#pragma unroll
        for (int mt = 0; mt < 4; ++mt) {
            bf16x8 av = *(const bf16x8*)&vt[(h * 64 + mt * 16 + l15) * 8 + quad * 8];
            f32x4 o = __builtin_amdgcn_mfma_f32_16x16x32_bf16(av, pf, (f32x4){0.f,0.f,0.f,0.f}, 0, 0, 0);
            if (l15 < 6) {
                const int px = mt * 16 + quad * 4;
                const int r = px >> 3, c0 = px & 7;
                const int gy = (wy * 8 + r + shift) & 127;
                const int gx0 = (wx * 8 + c0 + shift) & 127;
                size_t addr = ((size_t)(b * 96 + h * 6 + l15) * H_ + gy) * W_ + gx0;
                if (accumulate) {
                    ushort4 prev = *(const ushort4*)&obuf[addr];
                    o[0] = 0.5f * (o[0] + bf2f(prev.x));
                    o[1] = 0.5f * (o[1] + bf2f(prev.y));
                    o[2] = 0.5f * (o[2] + bf2f(prev.z));
                    o[3] = 0.5f * (o[3] + bf2f(prev.w));
                }
                ushort4 st = { f2bf(o[0]), f2bf(o[1]), f2bf(o[2]), f2bf(o[3]) };
                *(ushort4*)&obuf[addr] = st;
            }
        }
    }
}

// ---------------------------------------------------------------------------
// proj 1x1 GEMM + residual add; emits h2 bf16 (conv2 input). grid (2,64,16)
// ---------------------------------------------------------------------------
__global__ __launch_bounds__(256, 3)
void proj_gemm_kernel(const ushort_t* __restrict__ ob,
                      const float* __restrict__ pw,   // [96][96]
                      const float* __restrict__ pb,
                      const float* __restrict__ resid,
                      ushort_t* __restrict__ h2) {
    __shared__ __align__(16) ushort_t ti[2 * 64 * ICP];
    __shared__ __align__(16) ushort_t wc[96 * ICP];

    const int b = blockIdx.z;
    const int y0 = blockIdx.y * 2;
    const int x0 = blockIdx.x * 64;
    const int tid = threadIdx.x;
    const int wv = tid >> 6, lane = tid & 63;
    const int l15 = lane & 15, quad = lane >> 4;

    for (int idx = tid; idx < 2 * 96 * 64; idx += 256) {
        int xi = idx % 64;
        int t2 = idx / 64;
        int ic = t2 % 96;
        int r  = t2 / 96;
        ti[(r * 64 + xi) * ICP + ic] = ob[((b * 96 + ic) * H_ + y0 + r) * W_ + x0 + xi];
    }
    for (int idx = tid; idx < 96 * 96; idx += 256) {
        int ic = idx % 96;
        int oc = idx / 96;
        wc[oc * ICP + ic] = f2bf(pw[oc * 96 + ic]);
    }
    __syncthreads();

    f32x4 acc[2][6];
#pragma unroll
    for (int m = 0; m < 2; ++m)
#pragma unroll
        for (int nt = 0; nt < 6; ++nt) acc[m][nt] = (f32x4){0.f, 0.f, 0.f, 0.f};

#pragma unroll
    for (int ck = 0; ck < 3; ++ck) {
        const int kbase = ck * 32 + quad * 8;
        bf16x8 a0 = *(const bf16x8*)&ti[(0 * 64 + wv * 16 + l15) * ICP + kbase];
        bf16x8 a1 = *(const bf16x8*)&ti[(1 * 64 + wv * 16 + l15) * ICP + kbase];
#pragma unroll
        for (int nt = 0; nt < 6; ++nt) {
            bf16x8 bv = *(const bf16x8*)&wc[(nt * 16 + l15) * ICP + kbase];
            acc[0][nt] = __builtin_amdgcn_mfma_f32_16x16x32_bf16(a0, bv, acc[0][nt], 0, 0, 0);
            acc[1][nt] = __builtin_amdgcn_mfma_f32_16x16x32_bf16(a1, bv, acc[1][nt], 0, 0, 0);
        }
    }

#pragma unroll
    for (int m = 0; m < 2; ++m) {
        const int gy = y0 + m;
        const int gx = x0 + wv * 16 + quad * 4;
#pragma unroll
        for (int nt = 0; nt < 6; ++nt) {
            const int oc = nt * 16 + l15;
            const float bz2 = pb[oc];
            size_t addr = ((size_t)(b * 96 + oc) * H_ + gy) * W_ + gx;
            float4 rv = *(const float4*)&resid[addr];
            ushort4 u = { f2bf(acc[m][nt][0] + bz2 + rv.x),
                          f2bf(acc[m][nt][1] + bz2 + rv.y),
                          f2bf(acc[m][nt][2] + bz2 + rv.z),
                          f2bf(acc[m][nt][3] + bz2 + rv.w) };
            *(ushort4*)&h2[addr] = u;
        }
    }
}

// ---------------------------------------------------------------------------
extern "C" void kernel_launch(void* const* d_in, const int* in_sizes, int n_in,
                              void* d_out, int out_size, void* d_ws, size_t ws_size,
                              hipStream_t stream) {
    const float* x     = (const float*)d_in[0];
    const float* t_emb = (const float*)d_in[1];
    const float* w1    = (const float*)d_in[2];
    const float* b1    = (const float*)d_in[3];
    const float* g1    = (const float*)d_in[4];
    const float* be1   = (const float*)d_in[5];
    const float* wt    = (const float*)d_in[6];
    const float* bt    = (const float*)d_in[7];
    const float* qkv_w = (const float*)d_in[8];
    const float* qkv_b = (const float*)d_in[9];
    const float* proj_w= (const float*)d_in[10];
    const float* proj_b= (const float*)d_in[11];
    const float* ga    = (const float*)d_in[12];
    const float* ba    = (const float*)d_in[13];
    const float* w2    = (const float*)d_in[14];
    const float* b2    = (const float*)d_in[15];
    const float* g2    = (const float*)d_in[16];
    const float* be2   = (const float*)d_in[17];

    float* out = (float*)d_out;

    // Workspace arena (total 8*PLANE + 13824 bytes — same footprint as R2):
    // A: PLANE bf16  — xbf1 -> xq -> Obuf
    // B: 3*PLANE bf16 — qkvbuf -> h2 (first PLANE)
    ushort_t* A  = (ushort_t*)d_ws;
    ushort_t* Bq = A + PLANE_;
    float* stats = (float*)(Bq + 3 * PLANE_);   // 384 floats
    float* tvec  = stats + 384;                 // 3072 floats

    hipMemsetAsync(stats, 0, 384 * sizeof(float), stream);
    temb_kernel<<<12, 256, 0, stream>>>(t_emb, wt, bt, tvec);

    // conv1: x -> y1 (d_out), stats1
    castbf_kernel<<<(int)(PLANE_ / 4 / 256), 256, 0, stream>>>(x, A, (int)(PLANE_ / 4));
    conv3x3_mfma_kernel<<<dim3(2, 64, 16), 256, 0, stream>>>(A, w1, b1, out, stats);

    // h = silu(GN(y1))*(1+shift)+bias, in-place on d_out; stats2
    apply1_kernel<<<B_ * C_, 256, 0, stream>>>(out, stats, g1, be1, tvec, out, stats + 128);
    // xq = bf16(GN(h; ga, ba)) -> A
    gn_bf16_kernel<<<B_ * C_, 256, 0, stream>>>(out, stats + 128, ga, ba, A);

    // qkv = conv1x1(xq) -> B (288 bf16 planes per batch)
    qkv_gemm_kernel<<<dim3(2, 64, 48), 256, 0, stream>>>(A, qkv_w, qkv_b, Bq);

    // attention: O0 -> A; then A = 0.5*(O0 + O4)
    attn_kernel<<<dim3(16, 16, 16), 256, 0, stream>>>(Bq, A, 0, 0);
    attn_kernel<<<dim3(16, 16, 16), 256, 0, stream>>>(Bq, A, 4, 1);

    // h2 = h + proj(A) + pb -> Bq (bf16)
    proj_gemm_kernel<<<dim3(2, 64, 16), 256, 0, stream>>>(A, proj_w, proj_b, out, Bq);

    // conv2: h2 -> y2 (d_out), stats3
    conv3x3_mfma_kernel<<<dim3(2, 64, 16), 256, 0, stream>>>(Bq, w2, b2, out, stats + 256);

    // out = silu(GN(y2)), in-place
    gn_apply_kernel<<<B_ * C_, 256, 0, stream>>>(out, stats + 256, g2, be2, out, 1);
}

// Round 4
// 1370.923 us; speedup vs baseline: 5.3933x; 1.5791x over previous
//
#include <hip/hip_runtime.h>

// Problem constants
#define B_   16
#define C_   96
#define H_   128
#define W_   128
#define HW_  16384
#define CPG_ 24
#define NPG_ 393216.0f
#define TDIM_ 256
#define PLANE_ ((size_t)B_ * C_ * HW_)   // 25165824

typedef unsigned short ushort_t;
typedef __bf16 bf16x8 __attribute__((ext_vector_type(8)));
typedef float  f32x4  __attribute__((ext_vector_type(4)));

#define ICP 104   // padded K-stride in LDS (bf16 elems), 16B-aligned rows

__device__ __forceinline__ float silu_f(float x) { return x / (1.f + __expf(-x)); }
__device__ __forceinline__ float bf2f(ushort_t u) {
    union { float f; unsigned int i; } x; x.i = ((unsigned int)u) << 16; return x.f;
}
__device__ __forceinline__ ushort_t f2bf(float f) {
    __bf16 h = (__bf16)f; return *(ushort_t*)&h;
}

// ---------------------------------------------------------------------------
// t = silu(t_emb @ wt.T + bt) -> tvec[B][192]
// ---------------------------------------------------------------------------
__global__ void temb_kernel(const float* __restrict__ t_emb,
                            const float* __restrict__ wt,
                            const float* __restrict__ bt,
                            float* __restrict__ tvec) {
    int idx = blockIdx.x * 256 + threadIdx.x;
    if (idx >= B_ * 192) return;
    int b = idx / 192, o = idx - b * 192;
    float a = bt[o];
    const float* te = t_emb + b * TDIM_;
    const float* wr = wt + o * TDIM_;
    for (int k = 0; k < TDIM_; ++k) a += te[k] * wr[k];
    tvec[idx] = silu_f(a);
}

// ---------------------------------------------------------------------------
// fp32 -> bf16 cast
// ---------------------------------------------------------------------------
__global__ void castbf_kernel(const float* __restrict__ src,
                              ushort_t* __restrict__ dst, int n4) {
    int i = blockIdx.x * 256 + threadIdx.x;
    if (i >= n4) return;
    float4 v = ((const float4*)src)[i];
    ushort4 u = { f2bf(v.x), f2bf(v.y), f2bf(v.z), f2bf(v.w) };
    ((ushort4*)dst)[i] = u;
}

// ---------------------------------------------------------------------------
// conv3x3 implicit-GEMM MFMA (bf16 in, fp32 w cast in staging) + bias + GN stats
// ---------------------------------------------------------------------------
__global__ __launch_bounds__(256, 2)
void conv3x3_mfma_kernel(const ushort_t* __restrict__ xbf,
                         const float* __restrict__ w,     // [oc][ic][3][3] fp32
                         const float* __restrict__ bias,
                         float* __restrict__ out,
                         float* __restrict__ stats) {
    __shared__ __align__(16) ushort_t ti[4 * 66 * ICP];
    __shared__ __align__(16) ushort_t wc[96 * ICP];
    __shared__ float red[4][96][2];

    const int b   = blockIdx.z;
    const int y0  = blockIdx.y * 2;
    const int x0  = blockIdx.x * 64;
    const int tid = threadIdx.x;
    const int wv   = tid >> 6;
    const int lane = tid & 63;
    const int l15  = lane & 15;
    const int quad = lane >> 4;

    for (int idx = tid; idx < 4 * 96 * 66; idx += 256) {
        int xi = idx % 66;
        int t2 = idx / 66;
        int ic = t2 % 96;
        int r  = t2 / 96;
        int gy = y0 - 1 + r, gx = x0 - 1 + xi;
        ushort_t v = 0;
        if (gy >= 0 && gy < H_ && gx >= 0 && gx < W_)
            v = xbf[((b * 96 + ic) * H_ + gy) * W_ + gx];
        ti[(r * 66 + xi) * ICP + ic] = v;
    }

    f32x4 acc[2][6];
#pragma unroll
    for (int m = 0; m < 2; ++m)
#pragma unroll
        for (int nt = 0; nt < 6; ++nt)
            acc[m][nt] = (f32x4){0.f, 0.f, 0.f, 0.f};

    for (int kk = 0; kk < 9; ++kk) {
        const int ky = kk / 3, kx = kk - ky * 3;
        __syncthreads();
        for (int idx = tid; idx < 96 * 96; idx += 256) {
            int ic = idx % 96;
            int oc = idx / 96;
            wc[oc * ICP + ic] = f2bf(w[(oc * 96 + ic) * 9 + kk]);
        }
        __syncthreads();
#pragma unroll 1
        for (int ck = 0; ck < 3; ++ck) {
            const int kbase = ck * 32 + quad * 8;
            bf16x8 a0 = *(const bf16x8*)&ti[((0 + ky) * 66 + (wv * 16 + l15 + kx)) * ICP + kbase];
            bf16x8 a1 = *(const bf16x8*)&ti[((1 + ky) * 66 + (wv * 16 + l15 + kx)) * ICP + kbase];
#pragma unroll
            for (int nt = 0; nt < 6; ++nt) {
                bf16x8 bv = *(const bf16x8*)&wc[(nt * 16 + l15) * ICP + kbase];
                acc[0][nt] = __builtin_amdgcn_mfma_f32_16x16x32_bf16(a0, bv, acc[0][nt], 0, 0, 0);
                acc[1][nt] = __builtin_amdgcn_mfma_f32_16x16x32_bf16(a1, bv, acc[1][nt], 0, 0, 0);
            }
        }
    }

    float lsum[6], lsq[6];
#pragma unroll
    for (int nt = 0; nt < 6; ++nt) { lsum[nt] = 0.f; lsq[nt] = 0.f; }

#pragma unroll
    for (int m = 0; m < 2; ++m) {
        const int gy = y0 + m;
        const int gx = x0 + wv * 16 + quad * 4;
#pragma unroll
        for (int nt = 0; nt < 6; ++nt) {
            const int oc = nt * 16 + l15;
            const float bz = bias[oc];
            float v0 = acc[m][nt][0] + bz;
            float v1 = acc[m][nt][1] + bz;
            float v2 = acc[m][nt][2] + bz;
            float v3 = acc[m][nt][3] + bz;
            float4 vv = make_float4(v0, v1, v2, v3);
            *(float4*)&out[((b * 96 + oc) * H_ + gy) * W_ + gx] = vv;
            lsum[nt] += v0 + v1 + v2 + v3;
            lsq[nt]  += v0 * v0 + v1 * v1 + v2 * v2 + v3 * v3;
        }
    }
#pragma unroll
    for (int nt = 0; nt < 6; ++nt) {
        float s = lsum[nt], q = lsq[nt];
        s += __shfl_down(s, 32, 64);
        s += __shfl_down(s, 16, 64);
        q += __shfl_down(q, 32, 64);
        q += __shfl_down(q, 16, 64);
        if (lane < 16) {
            red[wv][nt * 16 + lane][0] = s;
            red[wv][nt * 16 + lane][1] = q;
        }
    }
    __syncthreads();
    if (tid < 8) {
        const int g = tid >> 1, which = tid & 1;
        float v = 0.f;
        for (int oc = g * CPG_; oc < g * CPG_ + CPG_; ++oc)
            for (int w2 = 0; w2 < 4; ++w2) v += red[w2][oc][which];
        atomicAdd(&stats[(b * 4 + g) * 2 + which], v);
    }
}

// ---------------------------------------------------------------------------
// h = silu(GN(y)) * (1+shift) + bias  (IN-PLACE on d_out), emits stats2
// ---------------------------------------------------------------------------
__global__ void apply1_kernel(const float* y,
                              const float* __restrict__ stats1,
                              const float* __restrict__ g1,
                              const float* __restrict__ be1,
                              const float* __restrict__ tvec,
                              float* h,
                              float* __restrict__ stats2) {
    const int bc = blockIdx.x;
    const int b = bc / C_, c = bc - b * C_;
    const int g = c / CPG_;
    const float sum = stats1[(b * 4 + g) * 2], sumsq = stats1[(b * 4 + g) * 2 + 1];
    const float mean = sum / NPG_;
    const float var  = sumsq / NPG_ - mean * mean;
    const float rstd = rsqrtf(var + 1e-5f);
    const float sc = rstd * g1[c];
    const float sh = be1[c] - mean * sc;
    const float tsc = 1.f + tvec[b * 192 + c];
    const float tbi = tvec[b * 192 + 96 + c];

    const float4* yp = (const float4*)(y + (size_t)bc * HW_);
    float4* hp = (float4*)(h + (size_t)bc * HW_);
    float ls = 0.f, lss = 0.f;
    for (int i = threadIdx.x; i < HW_ / 4; i += 256) {
        float4 v = yp[i];
        float r0 = silu_f(v.x * sc + sh) * tsc + tbi;
        float r1 = silu_f(v.y * sc + sh) * tsc + tbi;
        float r2 = silu_f(v.z * sc + sh) * tsc + tbi;
        float r3 = silu_f(v.w * sc + sh) * tsc + tbi;
        hp[i] = make_float4(r0, r1, r2, r3);
        ls  += r0 + r1 + r2 + r3;
        lss += r0*r0 + r1*r1 + r2*r2 + r3*r3;
    }
    for (int off = 32; off > 0; off >>= 1) {
        ls  += __shfl_down(ls, off, 64);
        lss += __shfl_down(lss, off, 64);
    }
    if ((threadIdx.x & 63) == 0) {
        atomicAdd(&stats2[(b * 4 + g) * 2 + 0], ls);
        atomicAdd(&stats2[(b * 4 + g) * 2 + 1], lss);
    }
}

// ---------------------------------------------------------------------------
// GN apply -> bf16 output (qkv GEMM input)
// ---------------------------------------------------------------------------
__global__ void gn_bf16_kernel(const float* __restrict__ in,
                               const float* __restrict__ stats,
                               const float* __restrict__ gamma,
                               const float* __restrict__ beta,
                               ushort_t* __restrict__ outb) {
    const int bc = blockIdx.x;
    const int b = bc / C_, c = bc - b * C_;
    const int g = c / CPG_;
    const float sum = stats[(b * 4 + g) * 2], sumsq = stats[(b * 4 + g) * 2 + 1];
    const float mean = sum / NPG_;
    const float var  = sumsq / NPG_ - mean * mean;
    const float rstd = rsqrtf(var + 1e-5f);
    const float sc = rstd * gamma[c];
    const float sh = beta[c] - mean * sc;
    const float4* ip = (const float4*)(in + (size_t)bc * HW_);
    ushort4* op = (ushort4*)(outb + (size_t)bc * HW_);
    for (int i = threadIdx.x; i < HW_ / 4; i += 256) {
        float4 v = ip[i];
        ushort4 u = { f2bf(v.x * sc + sh), f2bf(v.y * sc + sh),
                      f2bf(v.z * sc + sh), f2bf(v.w * sc + sh) };
        op[i] = u;
    }
}

// ---------------------------------------------------------------------------
// GN apply fp32 (+silu), in-place capable
// ---------------------------------------------------------------------------
__global__ void gn_apply_kernel(const float* in,
                                const float* __restrict__ stats,
                                const float* __restrict__ gamma,
                                const float* __restrict__ beta,
                                float* out, int dosilu) {
    const int bc = blockIdx.x;
    const int b = bc / C_, c = bc - b * C_;
    const int g = c / CPG_;
    const float sum = stats[(b * 4 + g) * 2], sumsq = stats[(b * 4 + g) * 2 + 1];
    const float mean = sum / NPG_;
    const float var  = sumsq / NPG_ - mean * mean;
    const float rstd = rsqrtf(var + 1e-5f);
    const float sc = rstd * gamma[c];
    const float sh = beta[c] - mean * sc;
    const float4* ip = (const float4*)(in + (size_t)bc * HW_);
    float4* op = (float4*)(out + (size_t)bc * HW_);
    for (int i = threadIdx.x; i < HW_ / 4; i += 256) {
        float4 v = ip[i];
        float r0 = v.x * sc + sh, r1 = v.y * sc + sh;
        float r2 = v.z * sc + sh, r3 = v.w * sc + sh;
        if (dosilu) { r0 = silu_f(r0); r1 = silu_f(r1); r2 = silu_f(r2); r3 = silu_f(r3); }
        op[i] = make_float4(r0, r1, r2, r3);
    }
}

// ---------------------------------------------------------------------------
// qkv 1x1 GEMM: out plane ocg = s*96+oc, bf16. grid (2, 64, 48): z = b*3+s
// ---------------------------------------------------------------------------
__global__ __launch_bounds__(256, 3)
void qkv_gemm_kernel(const ushort_t* __restrict__ xq,
                     const float* __restrict__ qw,   // [288][96]
                     const float* __restrict__ qb,
                     ushort_t* __restrict__ qkvbuf) {
    __shared__ __align__(16) ushort_t ti[2 * 64 * ICP];
    __shared__ __align__(16) ushort_t wc[96 * ICP];

    const int bz = blockIdx.z;
    const int b = bz / 3, s = bz - b * 3;
    const int y0 = blockIdx.y * 2;
    const int x0 = blockIdx.x * 64;
    const int tid = threadIdx.x;
    const int wv = tid >> 6, lane = tid & 63;
    const int l15 = lane & 15, quad = lane >> 4;

    for (int idx = tid; idx < 2 * 96 * 64; idx += 256) {
        int xi = idx % 64;
        int t2 = idx / 64;
        int ic = t2 % 96;
        int r  = t2 / 96;
        ti[(r * 64 + xi) * ICP + ic] = xq[((b * 96 + ic) * H_ + y0 + r) * W_ + x0 + xi];
    }
    for (int idx = tid; idx < 96 * 96; idx += 256) {
        int ic = idx % 96;
        int oc = idx / 96;
        wc[oc * ICP + ic] = f2bf(qw[(s * 96 + oc) * 96 + ic]);
    }
    __syncthreads();

    f32x4 acc[2][6];
#pragma unroll
    for (int m = 0; m < 2; ++m)
#pragma unroll
        for (int nt = 0; nt < 6; ++nt) acc[m][nt] = (f32x4){0.f, 0.f, 0.f, 0.f};

#pragma unroll
    for (int ck = 0; ck < 3; ++ck) {
        const int kbase = ck * 32 + quad * 8;
        bf16x8 a0 = *(const bf16x8*)&ti[(0 * 64 + wv * 16 + l15) * ICP + kbase];
        bf16x8 a1 = *(const bf16x8*)&ti[(1 * 64 + wv * 16 + l15) * ICP + kbase];
#pragma unroll
        for (int nt = 0; nt < 6; ++nt) {
            bf16x8 bv = *(const bf16x8*)&wc[(nt * 16 + l15) * ICP + kbase];
            acc[0][nt] = __builtin_amdgcn_mfma_f32_16x16x32_bf16(a0, bv, acc[0][nt], 0, 0, 0);
            acc[1][nt] = __builtin_amdgcn_mfma_f32_16x16x32_bf16(a1, bv, acc[1][nt], 0, 0, 0);
        }
    }

#pragma unroll
    for (int m = 0; m < 2; ++m) {
        const int gy = y0 + m;
        const int gx = x0 + wv * 16 + quad * 4;
#pragma unroll
        for (int nt = 0; nt < 6; ++nt) {
            const int ocg = s * 96 + nt * 16 + l15;
            const float bz2 = qb[ocg];
            ushort4 u = { f2bf(acc[m][nt][0] + bz2), f2bf(acc[m][nt][1] + bz2),
                          f2bf(acc[m][nt][2] + bz2), f2bf(acc[m][nt][3] + bz2) };
            *(ushort4*)&qkvbuf[((size_t)(b * 288 + ocg) * H_ + gy) * W_ + gx] = u;
        }
    }
}

// ---------------------------------------------------------------------------
// Attention v2: block per (head, window-row, batch). Stages Q/K/V row-slices
// into LDS with coalesced 256B row reads (pre-rotated by shift so windows are
// LDS-contiguous), then R3's verified MFMA S/softmax/O math sourced from LDS.
// O staged in LDS, written back coalesced; pass2 blends 0.5*(O0+O4).
// LDS strides 1032 (2064B) break the 2048B power-of-2 channel stride that
// would 16-way-conflict the ds_read_b128 fragment reads.
// ---------------------------------------------------------------------------
#define QKS 1032   // qk/ost channel stride (bf16 elems)
__global__ __launch_bounds__(256, 2)
void attn2_kernel(const ushort_t* __restrict__ qkv,
                  ushort_t* __restrict__ obuf, int shift, int accumulate) {
    __shared__ __align__(16) ushort_t qk[12 * QKS];        // Q d=0..5, K d=6..11
    __shared__ __align__(16) ushort_t vt[16 * 512 + 32];   // [wx][px][8] slots, zero-padded
    __shared__ __align__(16) ushort_t ost[6 * QKS];        // O staging [d][r][128]

    const int h = blockIdx.x, wy = blockIdx.y, b = blockIdx.z;
    const int tid = threadIdx.x;
    const int wv = tid >> 6, lane = tid & 63;
    const int l15 = lane & 15, quad = lane >> 4;

    // zero vt (slots 6,7 and pad must be 0; NaN*0=NaN safety)
    for (int i = tid; i < (16 * 512 + 32) / 2; i += 256) ((unsigned int*)vt)[i] = 0u;
    __syncthreads();

    // stage: 18 ch x 8 rows x 16 x-chunks of 8 px
    for (int idx = tid; idx < 2304; idx += 256) {
        int xc = idx & 15;
        int t2 = idx >> 4;
        int r  = t2 & 7;
        int ch = t2 >> 3;                 // 0..17
        int part = ch / 6, d = ch - part * 6;
        int gch = part * 96 + h * 6 + d;  // q / k / v plane
        int gy = (wy * 8 + r + shift) & 127;
        size_t rowb = ((size_t)(b * 288 + gch) * H_ + gy) * W_;
        ushort4 u0, u1;
        if (shift == 0) {
            u0 = *(const ushort4*)&qkv[rowb + xc * 8];
            u1 = *(const ushort4*)&qkv[rowb + xc * 8 + 4];
        } else {
            u0 = *(const ushort4*)&qkv[rowb + ((xc * 8 + 4) & 127)];
            u1 = *(const ushort4*)&qkv[rowb + ((xc * 8 + 8) & 127)];
        }
        if (part < 2) {
            ushort_t* dst = &qk[(part * 6 + d) * QKS + r * 128 + xc * 8];
            *(ushort4*)dst = u0;
            *(ushort4*)(dst + 4) = u1;
        } else {
            ushort_t uu[8] = {u0.x, u0.y, u0.z, u0.w, u1.x, u1.y, u1.z, u1.w};
            ushort_t* base = &vt[xc * 512 + (r * 8) * 8 + d];
#pragma unroll
            for (int c = 0; c < 8; ++c) base[c * 8] = uu[c];
        }
    }
    __syncthreads();

    const float scale = 0.40824829046386302f;  // 6^-0.5
    const int dcl = (l15 < 6) ? l15 : 5;       // clamp garbage lanes in-bounds
    const int chA = 6 + dcl;                   // K row e
    const int chB = dcl;                       // Q row d

    for (int i = 0; i < 4; ++i) {
        const int wx = wv * 4 + i;
        // ---- S^T = K Q^T (m=e, n=d, k=px)
        f32x4 sa = (f32x4){0.f, 0.f, 0.f, 0.f};
#pragma unroll
        for (int ck = 0; ck < 2; ++ck) {
            const int r = ck * 4 + quad;
            bf16x8 af  = *(const bf16x8*)&qk[chA * QKS + r * 128 + wx * 8];
            bf16x8 bfv = *(const bf16x8*)&qk[chB * QKS + r * 128 + wx * 8];
            sa = __builtin_amdgcn_mfma_f32_16x16x32_bf16(af, bfv, sa, 0, 0, 0);
        }
        // lane holds S^T[e=quad*4+reg][d=l15]; valid: quad0 regs0-3, quad1 regs0-1
        float s0 = sa[0] * scale, s1 = sa[1] * scale, s2 = sa[2] * scale, s3 = sa[3] * scale;
        float m = -3.4e38f;
        if (quad == 0) m = fmaxf(fmaxf(s0, s1), fmaxf(s2, s3));
        else if (quad == 1) m = fmaxf(s0, s1);
        m = fmaxf(m, __shfl_xor(m, 16, 64));
        m = fmaxf(m, __shfl_xor(m, 32, 64));
        float p0 = (quad <= 1) ? __expf(s0 - m) : 0.f;
        float p1 = (quad <= 1) ? __expf(s1 - m) : 0.f;
        float p2 = (quad == 0) ? __expf(s2 - m) : 0.f;
        float p3 = (quad == 0) ? __expf(s3 - m) : 0.f;
        float sum = p0 + p1 + p2 + p3;
        sum += __shfl_xor(sum, 16, 64);
        sum += __shfl_xor(sum, 32, 64);
        float inv = 1.f / sum;
        p0 *= inv; p1 *= inv; p2 *= inv; p3 *= inv;
        float e4 = __shfl_xor(p0, 16, 64);
        float e5 = __shfl_xor(p1, 16, 64);
        bf16x8 pf;
        pf[0] = (__bf16)p0; pf[1] = (__bf16)p1; pf[2] = (__bf16)p2; pf[3] = (__bf16)p3;
        pf[4] = (__bf16)e4; pf[5] = (__bf16)e5;
        pf[6] = (__bf16)0.f; pf[7] = (__bf16)0.f;
        if (quad != 0) { bf16x8 z = {}; pf = z; }
        // ---- O^T tiles: m=px (4 tiles of 16), n=d
#pragma unroll
        for (int mt = 0; mt < 4; ++mt) {
            bf16x8 av = *(const bf16x8*)&vt[wx * 512 + (mt * 16 + l15) * 8 + quad * 8];
            f32x4 o = __builtin_amdgcn_mfma_f32_16x16x32_bf16(av, pf, (f32x4){0.f,0.f,0.f,0.f}, 0, 0, 0);
            if (l15 < 6) {
                const int px = mt * 16 + quad * 4;
                const int r = px >> 3, c = px & 7;
                ushort4 st = { f2bf(o[0]), f2bf(o[1]), f2bf(o[2]), f2bf(o[3]) };
                *(ushort4*)&ost[l15 * QKS + r * 128 + wx * 8 + c] = st;
            }
        }
    }
    __syncthreads();

    // coalesced write-out: 6 ch x 8 rows x 16 chunks
    for (int idx = tid; idx < 768; idx += 256) {
        int xc = idx & 15;
        int t2 = idx >> 4;
        int r = t2 & 7, d = t2 >> 3;
        int gy = (wy * 8 + r + shift) & 127;
        size_t rowb = ((size_t)(b * 96 + h * 6 + d) * H_ + gy) * W_;
        size_t a0, a1;
        if (shift == 0) { a0 = rowb + xc * 8; a1 = rowb + xc * 8 + 4; }
        else { a0 = rowb + ((xc * 8 + 4) & 127); a1 = rowb + ((xc * 8 + 8) & 127); }
        const ushort_t* src = &ost[d * QKS + r * 128 + xc * 8];
        ushort4 v0 = *(const ushort4*)src;
        ushort4 v1 = *(const ushort4*)(src + 4);
        if (accumulate) {
            ushort4 q0 = *(const ushort4*)&obuf[a0];
            ushort4 q1 = *(const ushort4*)&obuf[a1];
            v0.x = f2bf(0.5f * (bf2f(v0.x) + bf2f(q0.x)));
            v0.y = f2bf(0.5f * (bf2f(v0.y) + bf2f(q0.y)));
            v0.z = f2bf(0.5f * (bf2f(v0.z) + bf2f(q0.z)));
            v0.w = f2bf(0.5f * (bf2f(v0.w) + bf2f(q0.w)));
            v1.x = f2bf(0.5f * (bf2f(v1.x) + bf2f(q1.x)));
            v1.y = f2bf(0.5f * (bf2f(v1.y) + bf2f(q1.y)));
            v1.z = f2bf(0.5f * (bf2f(v1.z) + bf2f(q1.z)));
            v1.w = f2bf(0.5f * (bf2f(v1.w) + bf2f(q1.w)));
        }
        *(ushort4*)&obuf[a0] = v0;
        *(ushort4*)&obuf[a1] = v1;
    }
}

// ---------------------------------------------------------------------------
// proj 1x1 GEMM + residual add; emits h2 bf16 (conv2 input). grid (2,64,16)
// ---------------------------------------------------------------------------
__global__ __launch_bounds__(256, 3)
void proj_gemm_kernel(const ushort_t* __restrict__ ob,
                      const float* __restrict__ pw,   // [96][96]
                      const float* __restrict__ pb,
                      const float* __restrict__ resid,
                      ushort_t* __restrict__ h2) {
    __shared__ __align__(16) ushort_t ti[2 * 64 * ICP];
    __shared__ __align__(16) ushort_t wc[96 * ICP];

    const int b = blockIdx.z;
    const int y0 = blockIdx.y * 2;
    const int x0 = blockIdx.x * 64;
    const int tid = threadIdx.x;
    const int wv = tid >> 6, lane = tid & 63;
    const int l15 = lane & 15, quad = lane >> 4;

    for (int idx = tid; idx < 2 * 96 * 64; idx += 256) {
        int xi = idx % 64;
        int t2 = idx / 64;
        int ic = t2 % 96;
        int r  = t2 / 96;
        ti[(r * 64 + xi) * ICP + ic] = ob[((b * 96 + ic) * H_ + y0 + r) * W_ + x0 + xi];
    }
    for (int idx = tid; idx < 96 * 96; idx += 256) {
        int ic = idx % 96;
        int oc = idx / 96;
        wc[oc * ICP + ic] = f2bf(pw[oc * 96 + ic]);
    }
    __syncthreads();

    f32x4 acc[2][6];
#pragma unroll
    for (int m = 0; m < 2; ++m)
#pragma unroll
        for (int nt = 0; nt < 6; ++nt) acc[m][nt] = (f32x4){0.f, 0.f, 0.f, 0.f};

#pragma unroll
    for (int ck = 0; ck < 3; ++ck) {
        const int kbase = ck * 32 + quad * 8;
        bf16x8 a0 = *(const bf16x8*)&ti[(0 * 64 + wv * 16 + l15) * ICP + kbase];
        bf16x8 a1 = *(const bf16x8*)&ti[(1 * 64 + wv * 16 + l15) * ICP + kbase];
#pragma unroll
        for (int nt = 0; nt < 6; ++nt) {
            bf16x8 bv = *(const bf16x8*)&wc[(nt * 16 + l15) * ICP + kbase];
            acc[0][nt] = __builtin_amdgcn_mfma_f32_16x16x32_bf16(a0, bv, acc[0][nt], 0, 0, 0);
            acc[1][nt] = __builtin_amdgcn_mfma_f32_16x16x32_bf16(a1, bv, acc[1][nt], 0, 0, 0);
        }
    }

#pragma unroll
    for (int m = 0; m < 2; ++m) {
        const int gy = y0 + m;
        const int gx = x0 + wv * 16 + quad * 4;
#pragma unroll
        for (int nt = 0; nt < 6; ++nt) {
            const int oc = nt * 16 + l15;
            const float bz2 = pb[oc];
            size_t addr = ((size_t)(b * 96 + oc) * H_ + gy) * W_ + gx;
            float4 rv = *(const float4*)&resid[addr];
            ushort4 u = { f2bf(acc[m][nt][0] + bz2 + rv.x),
                          f2bf(acc[m][nt][1] + bz2 + rv.y),
                          f2bf(acc[m][nt][2] + bz2 + rv.z),
                          f2bf(acc[m][nt][3] + bz2 + rv.w) };
            *(ushort4*)&h2[addr] = u;
        }
    }
}

// ---------------------------------------------------------------------------
extern "C" void kernel_launch(void* const* d_in, const int* in_sizes, int n_in,
                              void* d_out, int out_size, void* d_ws, size_t ws_size,
                              hipStream_t stream) {
    const float* x     = (const float*)d_in[0];
    const float* t_emb = (const float*)d_in[1];
    const float* w1    = (const float*)d_in[2];
    const float* b1    = (const float*)d_in[3];
    const float* g1    = (const float*)d_in[4];
    const float* be1   = (const float*)d_in[5];
    const float* wt    = (const float*)d_in[6];
    const float* bt    = (const float*)d_in[7];
    const float* qkv_w = (const float*)d_in[8];
    const float* qkv_b = (const float*)d_in[9];
    const float* proj_w= (const float*)d_in[10];
    const float* proj_b= (const float*)d_in[11];
    const float* ga    = (const float*)d_in[12];
    const float* ba    = (const float*)d_in[13];
    const float* w2    = (const float*)d_in[14];
    const float* b2    = (const float*)d_in[15];
    const float* g2    = (const float*)d_in[16];
    const float* be2   = (const float*)d_in[17];

    float* out = (float*)d_out;

    // Workspace arena:
    // A: PLANE bf16  — xbf1 -> xq -> Obuf
    // B: 3*PLANE bf16 — qkvbuf -> h2 (first PLANE)
    ushort_t* A  = (ushort_t*)d_ws;
    ushort_t* Bq = A + PLANE_;
    float* stats = (float*)(Bq + 3 * PLANE_);   // 384 floats
    float* tvec  = stats + 384;                 // 3072 floats

    hipMemsetAsync(stats, 0, 384 * sizeof(float), stream);
    temb_kernel<<<12, 256, 0, stream>>>(t_emb, wt, bt, tvec);

    // conv1: x -> y1 (d_out), stats1
    castbf_kernel<<<(int)(PLANE_ / 4 / 256), 256, 0, stream>>>(x, A, (int)(PLANE_ / 4));
    conv3x3_mfma_kernel<<<dim3(2, 64, 16), 256, 0, stream>>>(A, w1, b1, out, stats);

    // h = silu(GN(y1))*(1+shift)+bias, in-place on d_out; stats2
    apply1_kernel<<<B_ * C_, 256, 0, stream>>>(out, stats, g1, be1, tvec, out, stats + 128);
    // xq = bf16(GN(h; ga, ba)) -> A
    gn_bf16_kernel<<<B_ * C_, 256, 0, stream>>>(out, stats + 128, ga, ba, A);

    // qkv = conv1x1(xq) -> Bq (288 bf16 planes per batch)
    qkv_gemm_kernel<<<dim3(2, 64, 48), 256, 0, stream>>>(A, qkv_w, qkv_b, Bq);

    // attention: O0 -> A; then A = 0.5*(O0 + O4)
    attn2_kernel<<<dim3(16, 16, 16), 256, 0, stream>>>(Bq, A, 0, 0);
    attn2_kernel<<<dim3(16, 16, 16), 256, 0, stream>>>(Bq, A, 4, 1);

    // h2 = h + proj(A) + pb -> Bq (bf16)
    proj_gemm_kernel<<<dim3(2, 64, 16), 256, 0, stream>>>(A, proj_w, proj_b, out, Bq);

    // conv2: h2 -> y2 (d_out), stats3
    conv3x3_mfma_kernel<<<dim3(2, 64, 16), 256, 0, stream>>>(Bq, w2, b2, out, stats + 256);

    // out = silu(GN(y2)), in-place
    gn_apply_kernel<<<B_ * C_, 256, 0, stream>>>(out, stats + 256, g2, be2, out, 1);
}